// Round 15
// baseline (663.400 us; speedup 1.0000x reference)
//
#include <hip/hip_runtime.h>
#include <stdint.h>

#define BATCH 32
#define SEQ   2048
#define HDIM  1024

typedef short short8 __attribute__((ext_vector_type(8)));
typedef float f32x4 __attribute__((ext_vector_type(4)));

__device__ __forceinline__ unsigned short f2b(float f) {
    unsigned u = __float_as_uint(f);
    u += 0x7FFFu + ((u >> 16) & 1u);   // round-to-nearest-even
    return (unsigned short)(u >> 16);
}
// pack hi16(a) | hi16(b)<<16 in one v_perm_b32 (bf16 truncation)
__device__ __forceinline__ unsigned pk_bf16(float a, float b) {
    return __builtin_amdgcn_perm(__float_as_uint(b), __float_as_uint(a), 0x07060302u);
}
__device__ __forceinline__ float fast_tanh(float x) {
    float ex = __expf(2.0f * x);
    return 1.0f - 2.0f / (ex + 1.0f);
}
__device__ __forceinline__ void gl2lds16(const unsigned short* g, unsigned short* l) {
    __builtin_amdgcn_global_load_lds(
        (const __attribute__((address_space(1))) unsigned int*)g,
        (__attribute__((address_space(3))) unsigned int*)l, 16, 0, 0);
}

// ---------------------------------------------------------------------------
// Kernel 1 (fused prep + convert + out-init), block-role split:
//   blocks 0..2047   : convert -- enc fp32 -> bf16 (truncation), written as
//     the EXACT 16KB LDS image per (mtile, kt): img[r][P][8] = logical chunk
//     P^(r&7) of row r (GEMM swizzle baked in). COALESCED: each wave reads
//     ONE row at a time, 64 lanes x float4 = contiguous 1KB per instruction
//     (round-8 version gathered 16B from 32 different 4KB-strided rows).
//   blocks 2048..3071: prep (k = bid-2048) -- We row k -> bf16 (RNE);
//     qb = hidden.Wh^T + b; zero scores row.
//   blocks 3072..3103: out-init (b = bid-3072) -- zero context slots, copy
//     hidden into out (moved out of the old stats kernel).
// ---------------------------------------------------------------------------
__global__ __launch_bounds__(256) void prep_convert_kernel(
    const float* __restrict__ hidden, const float* __restrict__ attn_w,
    const float* __restrict__ attn_b, const float* __restrict__ enc,
    unsigned short* __restrict__ we_bf, unsigned short* __restrict__ enc_bf,
    float* __restrict__ qb, float* __restrict__ scores, float* out) {
    int bid = blockIdx.x;
    int tid = threadIdx.x;
    __shared__ float red[4][BATCH];

    if (bid < 2048) {
        // ---- convert role ----
        int m = bid >> 2, g = bid & 3;      // mtile, kt-group (4 kt each)
        int wv = tid >> 6, l = tid & 63;
        int ktl   = l >> 4;                 // 0..3 : kt within group
        int cpair = (l & 15) >> 1;          // 0..7 : logical 8-col chunk
        int half  = l & 1;                  // 0/1  : 4-col half of chunk
        const float* srcbase = enc + (size_t)m * 128 * HDIM + g * 256 + l * 4;
        unsigned short* imgk =
            enc_bf + ((size_t)m * 16 + g * 4 + ktl) * 8192 + half * 4;
#pragma unroll 4
        for (int it = 0; it < 32; ++it) {
            int r = it * 4 + wv;            // whole wave shares one row
            float4 v = *(const float4*)(srcbase + (size_t)r * HDIM);
            uint2 o;
            o.x = pk_bf16(v.x, v.y);
            o.y = pk_bf16(v.z, v.w);
            int p = cpair ^ (r & 7);
            *(uint2*)(imgk + r * 64 + p * 8) = o;
        }
        return;
    }

    if (bid >= 3072) {
        // ---- out-init role ----
        int b = bid - 3072;
        float4* dz = (float4*)(out + (size_t)b * 2048);
        const float4* hs = (const float4*)(hidden + (size_t)b * HDIM);
        float4 z; z.x = z.y = z.z = z.w = 0.0f;
        dz[tid] = z;                 // zero context slots (1024 floats)
        dz[256 + tid] = hs[tid];     // copy hidden (1024 floats)
        return;
    }

    // ---- prep role ----
    int k = bid - 2048;
    if (tid < 64) scores[(size_t)k * 64 + tid] = 0.0f;

    {
        const float4* src = (const float4*)(attn_w + (size_t)k * 2048 + 1024);
        float4 v = src[tid];
        ushort4 o;
        o.x = f2b(v.x); o.y = f2b(v.y); o.z = f2b(v.z); o.w = f2b(v.w);
        ((ushort4*)(we_bf + (size_t)k * HDIM))[tid] = o;
    }

    float part[BATCH];
#pragma unroll
    for (int b = 0; b < BATCH; ++b) part[b] = 0.0f;
    const float* wrow = attn_w + (size_t)k * 2048;
    for (int h = tid; h < HDIM; h += 256) {
        float w = wrow[h];
#pragma unroll
        for (int b = 0; b < BATCH; ++b) part[b] += w * hidden[b * HDIM + h];
    }
    int lane = tid & 63, wv = tid >> 6;
#pragma unroll
    for (int b = 0; b < BATCH; ++b) {
        float v = part[b];
        v += __shfl_xor(v, 1);  v += __shfl_xor(v, 2);  v += __shfl_xor(v, 4);
        v += __shfl_xor(v, 8);  v += __shfl_xor(v, 16); v += __shfl_xor(v, 32);
        if (lane == 0) red[wv][b] = v;
    }
    __syncthreads();
    if (tid < BATCH) {
        float v = red[0][tid] + red[1][tid] + red[2][tid] + red[3][tid] + attn_b[k];
        qb[(size_t)tid * HDIM + k] = v;
    }
}

// ---------------------------------------------------------------------------
// Kernel 2: score GEMM, 128x128 tile, BK=64, 256 threads (4 waves 2Mx2N,
// wave tile 64x64). DOUBLE-BUFFERED 64KB LDS, ONE barrier per K-tile:
//   STAGE(t+1 -> buf^1) issued FIRST, compute(buf) runs under the loads,
//   barrier (implicit vmcnt0) publishes the staged tile.
// Round-8's single-buffer compute->bar->STAGE->bar exposed full L2 latency
// per tile (MfmaUtil pinned at 34%); this hides it inside the block.
// Both A and B staged via global_load_lds from pre-swizzled bf16 buffers;
// swizzle chunk^(row&7): 0 bank conflicts (verified r4-r8). XCD decode:
// 8 consecutive per-XCD slots share one mtile -> A L2-served 8x (FETCH 83MB
// measured).
// ---------------------------------------------------------------------------
__global__ __launch_bounds__(256, 2) void score_gemm_kernel(
    const unsigned short* __restrict__ enc_bf,
    const unsigned short* __restrict__ we_bf,
    const float* __restrict__ qb, const float* __restrict__ v_w,
    float* __restrict__ scores) {
    __shared__ __align__(16) unsigned short As[2 * 8192];  // 32 KB
    __shared__ __align__(16) unsigned short Bs[2 * 8192];  // 32 KB

    int tid  = threadIdx.x;
    int lane = tid & 63, w = tid >> 6;     // 4 waves
    int wm = w & 1, wn = w >> 1;           // 2 x 2
    int i15 = lane & 15, q = lane >> 4;

    // XCD decode: xcd = raw&7; per-XCD slot i: ntile = i&7 (8 consecutive
    // slots share mtile), mtile = xcd*64 + (i>>3). Bijective over 4096.
    int raw   = blockIdx.x;
    int i     = raw >> 3;
    int ntile = i & 7;
    int mtile = (raw & 7) * 64 + (i >> 3);  // 0..511
    int n0 = ntile * 128;
    long gm0 = (long)mtile * 128;           // flat row base in [B*S]
    int b = mtile >> 4;

    // ---- B staging: wave w, instr j -> rows w*32+j*8+(lane>>3); source
    // pre-swizzled so LDS phys chunk p holds logical p^(r&7).
    int brow_in = lane >> 3;
    int bchunk  = (lane & 7) ^ ((lane >> 3) & 7);
    const unsigned short* Bg =
        we_bf + (size_t)(n0 + w * 32 + brow_in) * HDIM + bchunk * 8;
    int bdoff = (w * 32) * 64 + lane * 8;

    // ---- A staging: image is already the LDS byte pattern; linear copy.
    const unsigned short* Atile = enc_bf + (size_t)mtile * 16 * 8192;
    int aoff = w * 2048 + lane * 8;         // + j*512, j=0..3

    f32x4 acc[4][4];
#pragma unroll
    for (int mt = 0; mt < 4; ++mt)
#pragma unroll
        for (int nt = 0; nt < 4; ++nt) acc[mt][nt] = (f32x4)0.0f;

    int arow0 = wm * 64 + i15;    // + mt*16
    int brow0 = wn * 64 + i15;    // + nt*16

#define STAGE(KT, BUF) do {                                                   \
        unsigned short* Bd = Bs + (BUF) * 8192 + bdoff;                       \
        const unsigned short* bsrc = Bg + (size_t)(KT) * 64;                  \
        gl2lds16(bsrc,                     Bd);                               \
        gl2lds16(bsrc + (size_t)8  * HDIM, Bd + 512);                         \
        gl2lds16(bsrc + (size_t)16 * HDIM, Bd + 1024);                        \
        gl2lds16(bsrc + (size_t)24 * HDIM, Bd + 1536);                        \
        const unsigned short* asrc = Atile + (size_t)(KT) * 8192 + aoff;      \
        unsigned short* adst = As + (BUF) * 8192 + aoff;                      \
        gl2lds16(asrc,        adst);                                          \
        gl2lds16(asrc + 512,  adst + 512);                                    \
        gl2lds16(asrc + 1024, adst + 1024);                                   \
        gl2lds16(asrc + 1536, adst + 1536);                                   \
    } while (0)

    // prologue: stage K-tile 0 into buffer 0
    STAGE(0, 0);
    __syncthreads();

    for (int kt = 0; kt < 16; ++kt) {
        int cur = kt & 1;
        if (kt < 15) STAGE(kt + 1, cur ^ 1);   // loads fly under compute

        const unsigned short* Ac = As + cur * 8192;
        const unsigned short* Bc = Bs + cur * 8192;
        __builtin_amdgcn_s_setprio(1);
#pragma unroll
        for (int kk = 0; kk < 2; ++kk) {
            int xr = ((kk * 4 + q) ^ (i15 & 7)) * 8;
            short8 af[4], bf[4];
#pragma unroll
            for (int mt = 0; mt < 4; ++mt)
                af[mt] = *(const short8*)(Ac + (arow0 + mt * 16) * 64 + xr);
#pragma unroll
            for (int nt = 0; nt < 4; ++nt)
                bf[nt] = *(const short8*)(Bc + (brow0 + nt * 16) * 64 + xr);
#pragma unroll
            for (int mt = 0; mt < 4; ++mt)
#pragma unroll
                for (int nt = 0; nt < 4; ++nt)
                    acc[mt][nt] = __builtin_amdgcn_mfma_f32_16x16x32_bf16(
                        af[mt], bf[nt], acc[mt][nt], 0, 0, 0);
        }
        __builtin_amdgcn_s_setprio(0);

        if (kt < 15) __syncthreads();  // drains vmcnt -> staged tile ready;
                                       // WAR-protects buf cur for next stage
    }
#undef STAGE

    // epilogue: C layout col=i15 (n), row=q*4+reg (m); tanh + v-dot + n-reduce
    float sc[4][4];
#pragma unroll
    for (int mt = 0; mt < 4; ++mt)
#pragma unroll
        for (int r = 0; r < 4; ++r) sc[mt][r] = 0.0f;

#pragma unroll
    for (int nt = 0; nt < 4; ++nt) {
        int n = n0 + wn * 64 + nt * 16 + i15;
        float qv = qb[(size_t)b * HDIM + n];
        float vv = v_w[n];
#pragma unroll
        for (int mt = 0; mt < 4; ++mt)
#pragma unroll
            for (int r = 0; r < 4; ++r)
                sc[mt][r] += vv * fast_tanh(acc[mt][nt][r] + qv);
    }
#pragma unroll
    for (int mt = 0; mt < 4; ++mt)
#pragma unroll
        for (int r = 0; r < 4; ++r) {
            float v = sc[mt][r];
            v += __shfl_xor(v, 1); v += __shfl_xor(v, 2);
            v += __shfl_xor(v, 4); v += __shfl_xor(v, 8);
            if (i15 == 0)
                atomicAdd(&scores[gm0 + wm * 64 + mt * 16 + q * 4 + r], v);
        }
}

// ---------------------------------------------------------------------------
// Kernel 3: context + full softmax, stats recomputed per block (8KB L2-hit
// read, reduction sequence BIT-IDENTICAL to the old stats kernel). Computes
// w = expf(s-m)*inv, writes attn_weights output, accumulates context via
// atomicAdd into the pre-zeroed slots. grid = 32 b x 16 s-chunks.
// ---------------------------------------------------------------------------
__global__ __launch_bounds__(256) void context_kernel(
    const float* __restrict__ enc, const float* __restrict__ scores,
    float* out) {
    int id = blockIdx.x;
    int scid = id & 15, b = id >> 4;
    int tid = threadIdx.x;
    const float* srow = scores + (size_t)b * SEQ;
    __shared__ float redm[4];
    __shared__ float reds[4];
    __shared__ float wl[128];
    int lane = tid & 63, wv = tid >> 6;

    // ---- stats phase (identical ops/order to old softmax_stats) ----
    float loc[8];
    float m = -1e30f;
#pragma unroll
    for (int i = 0; i < 8; ++i) {
        loc[i] = srow[tid + i * 256];
        m = fmaxf(m, loc[i]);
    }
#pragma unroll
    for (int d = 1; d < 64; d <<= 1) m = fmaxf(m, __shfl_xor(m, d));
    if (lane == 0) redm[wv] = m;
    __syncthreads();
    m = fmaxf(fmaxf(redm[0], redm[1]), fmaxf(redm[2], redm[3]));

    float sum = 0.0f;
#pragma unroll
    for (int i = 0; i < 8; ++i) sum += __expf(loc[i] - m);
#pragma unroll
    for (int d = 1; d < 64; d <<= 1) sum += __shfl_xor(sum, d);
    if (lane == 0) reds[wv] = sum;
    __syncthreads();
    float inv = 1.0f / (reds[0] + reds[1] + reds[2] + reds[3]);

    // ---- weights for this 128-slice ----
    if (tid < 128) {
        float s = srow[scid * 128 + tid];
        float wgt = __expf(s - m) * inv;
        wl[tid] = wgt;
        out[BATCH * SEQ + (size_t)b * SEQ + scid * 128 + tid] = wgt;
    }
    __syncthreads();

    // ---- context accumulate ----
    const float* ebase = enc + ((size_t)(b * SEQ + scid * 128)) * HDIM + tid * 4;
    float a0 = 0.f, a1 = 0.f, a2 = 0.f, a3 = 0.f;
    float b0 = 0.f, b1 = 0.f, b2 = 0.f, b3 = 0.f;
#pragma unroll 4
    for (int s = 0; s < 64; ++s) {
        float4 e0 = *(const float4*)(ebase + (size_t)s * HDIM);
        float4 e1 = *(const float4*)(ebase + (size_t)(s + 64) * HDIM);
        float w0 = wl[s], w1 = wl[s + 64];
        a0 += w0 * e0.x; a1 += w0 * e0.y; a2 += w0 * e0.z; a3 += w0 * e0.w;
        b0 += w1 * e1.x; b1 += w1 * e1.y; b2 += w1 * e1.z; b3 += w1 * e1.w;
    }
    float* o = out + (size_t)b * 2048 + tid * 4;
    atomicAdd(o + 0, a0 + b0); atomicAdd(o + 1, a1 + b1);
    atomicAdd(o + 2, a2 + b2); atomicAdd(o + 3, a3 + b3);
}

// ---------------------------------------------------------------------------
extern "C" void kernel_launch(void* const* d_in, const int* in_sizes, int n_in,
                              void* d_out, int out_size, void* d_ws, size_t ws_size,
                              hipStream_t stream) {
    const float* hidden = (const float*)d_in[0];
    const float* enc    = (const float*)d_in[1];
    const float* attn_w = (const float*)d_in[2];
    const float* attn_b = (const float*)d_in[3];
    const float* v_w    = (const float*)d_in[4];
    float* out = (float*)d_out;

    char* ws = (char*)d_ws;
    unsigned short* enc_bf = (unsigned short*)ws;                        // 128 MB
    unsigned short* we_bf  = (unsigned short*)(ws + (size_t)134217728);  // 2 MB
    float* qb     = (float*)(ws + (size_t)134217728 + 2097152);          // 128 KB
    float* scores = (float*)(ws + (size_t)134217728 + 2097152 + 131072); // 256 KB

    prep_convert_kernel<<<3104, 256, 0, stream>>>(hidden, attn_w, attn_b, enc,
                                                  we_bf, enc_bf, qb, scores, out);
    score_gemm_kernel<<<4096, 256, 0, stream>>>(enc_bf, we_bf, qb, v_w, scores);
    context_kernel<<<512, 256, 0, stream>>>(enc, scores, out);
}